// Round 1
// baseline (300.629 us; speedup 1.0000x reference)
//
#include <hip/hip_runtime.h>

// DCE-MRI eTofts forward model.
// param: [B,3] f32, T10: [B,1] f32, cp: [B,T] f32  ->  out: [B,T] f32
// Per-row linear IIR over T, then pointwise SPGR signal equation.

static constexpr int   Bn     = 262144;
static constexpr int   Tn     = 112;
static constexpr float TRc    = 0.005f;
static constexpr float DELTT  = 0.075f;                 // 4.5/60
static constexpr float R1R    = 4.5f;
static constexpr float SIN_A  = 0.25881904510252074f;   // sin(15 deg)
static constexpr float COS_A  = 0.9659258262890683f;    // cos(15 deg)

__global__ __launch_bounds__(256) void etofts_kernel(
    const float* __restrict__ param,
    const float* __restrict__ T10,
    const float* __restrict__ cp,
    float* __restrict__ out)
{
    const int b = blockIdx.x * blockDim.x + threadIdx.x;
    if (b >= Bn) return;

    // Parameter scaling + clamping (clip = min(max(x,lo),hi))
    const float ktrans = fminf(fmaxf(param[3 * b + 0] * 0.2f, 1e-5f), 0.2f);
    const float vp     = fminf(fmaxf(param[3 * b + 1] * 0.1f, 0.0005f), 0.1f);
    const float ve     = fminf(fmaxf(param[3 * b + 2] * 0.6f, 0.04f), 0.6f);

    const float decay = __expf(-(ktrans / ve) * DELTT);
    const float r10   = 1.0f / T10[b];

    const float4* __restrict__ cp4  = (const float4*)(cp  + (size_t)b * Tn);
    float4* __restrict__       out4 = (float4*)(out + (size_t)b * Tn);

    float c = 0.0f;
    #pragma unroll 4
    for (int i = 0; i < Tn / 4; ++i) {
        float4 v = cp4[i];
        float4 o;
        float* vv = &v.x;
        float* oo = &o.x;
        #pragma unroll
        for (int j = 0; j < 4; ++j) {
            const float cpt = vv[j];
            c = c * decay + cpt * DELTT;            // IIR recurrence
            const float ct = vp * cpt + c * ktrans; // vp*cp + ce
            const float R1 = r10 + R1R * ct;
            const float E  = __expf(-TRc * R1);
            const float s  = (1.0f - E) * SIN_A / (1.0f - E * COS_A);
            oo[j] = s * 20.0f;
        }
        out4[i] = o;
    }
}

extern "C" void kernel_launch(void* const* d_in, const int* in_sizes, int n_in,
                              void* d_out, int out_size, void* d_ws, size_t ws_size,
                              hipStream_t stream) {
    const float* param = (const float*)d_in[0];
    const float* T10   = (const float*)d_in[1];
    const float* cp    = (const float*)d_in[2];
    float*       out   = (float*)d_out;

    const int threads = 256;
    const int blocks  = (Bn + threads - 1) / threads;
    etofts_kernel<<<blocks, threads, 0, stream>>>(param, T10, cp, out);
}

// Round 2
// 286.716 us; speedup vs baseline: 1.0485x; 1.0485x over previous
//
#include <hip/hip_runtime.h>

// DCE-MRI eTofts forward model, LDS-coalesced version.
// param: [B,3] f32, T10: [B,1] f32, cp: [B,T] f32  ->  out: [B,T] f32
//
// Block = 256 threads = 256 consecutive rows. T tiled 4 x 28.
// Global <-> LDS in coalesced float4 granules; LDS tile is transposed
// (lds[t][row], row-stride 257) so compute-phase reads are conflict-free
// (bank = (t+row)%32, consecutive lanes -> consecutive banks).

static constexpr int   Bn    = 262144;
static constexpr int   Tn    = 112;
static constexpr int   R     = 256;        // rows per block
static constexpr int   TT    = 28;         // timesteps per tile
static constexpr int   NT    = Tn / TT;    // 4 tiles
static constexpr int   RP    = R + 1;      // LDS stride (floats) between t-rows
static constexpr float TRc   = 0.005f;
static constexpr float DELTT = 0.075f;                 // 4.5/60
static constexpr float R1R   = 4.5f;
static constexpr float SIN_A = 0.25881904510252074f;   // sin(15 deg)
static constexpr float COS_A = 0.9659258262890683f;    // cos(15 deg)

__global__ __launch_bounds__(256) void etofts_kernel(
    const float* __restrict__ param,
    const float* __restrict__ T10,
    const float* __restrict__ cp,
    float* __restrict__ out)
{
    __shared__ float lds[TT * RP];         // 28 * 257 * 4 B = 28784 B

    const int k  = threadIdx.x;            // local row id (this thread's row)
    const int b0 = blockIdx.x * R;
    const int b  = b0 + k;

    // Parameter scaling + clamping
    const float ktrans = fminf(fmaxf(param[3 * b + 0] * 0.2f, 1e-5f), 0.2f);
    const float vp     = fminf(fmaxf(param[3 * b + 1] * 0.1f, 0.0005f), 0.1f);
    const float ve     = fminf(fmaxf(param[3 * b + 2] * 0.6f, 0.04f), 0.6f);
    const float decay  = __expf(-(ktrans / ve) * DELTT);
    const float r10    = 1.0f / T10[b];

    float c = 0.0f;                         // IIR state, carried across tiles

    for (int tile = 0; tile < NT; ++tile) {
        const int t0 = tile * TT;

        // ---- coalesced load of R x TT tile (float4 granules) ----
        // idx in [0, R*TT/4 = 1792): row = idx/7, col4 = idx%7 (TT/4 == 7)
        #pragma unroll
        for (int i = 0; i < (R * TT / 4) / 256; ++i) {   // 7 iterations
            const int idx  = i * 256 + k;
            const int row  = idx / 7;
            const int col4 = idx - row * 7;
            const float4 v = *(const float4*)(cp + (size_t)(b0 + row) * Tn + t0 + col4 * 4);
            const int tb = col4 * 4;
            lds[(tb + 0) * RP + row] = v.x;
            lds[(tb + 1) * RP + row] = v.y;
            lds[(tb + 2) * RP + row] = v.z;
            lds[(tb + 3) * RP + row] = v.w;
        }
        __syncthreads();

        // ---- compute in place (conflict-free column reads) ----
        #pragma unroll
        for (int t = 0; t < TT; ++t) {
            const float cpt = lds[t * RP + k];
            c = c * decay + cpt * DELTT;             // IIR recurrence
            const float ct = vp * cpt + c * ktrans;  // vp*cp + ce
            const float R1 = r10 + R1R * ct;
            const float E  = __expf(-TRc * R1);
            const float s  = (1.0f - E) * SIN_A / (1.0f - E * COS_A);
            lds[t * RP + k] = s * 20.0f;             // overwrite own slot: no race
        }
        __syncthreads();

        // ---- coalesced store ----
        #pragma unroll
        for (int i = 0; i < (R * TT / 4) / 256; ++i) {
            const int idx  = i * 256 + k;
            const int row  = idx / 7;
            const int col4 = idx - row * 7;
            const int tb = col4 * 4;
            float4 o;
            o.x = lds[(tb + 0) * RP + row];
            o.y = lds[(tb + 1) * RP + row];
            o.z = lds[(tb + 2) * RP + row];
            o.w = lds[(tb + 3) * RP + row];
            *(float4*)(out + (size_t)(b0 + row) * Tn + t0 + col4 * 4) = o;
        }
        __syncthreads();   // protect LDS before next tile's load overwrites
    }
}

extern "C" void kernel_launch(void* const* d_in, const int* in_sizes, int n_in,
                              void* d_out, int out_size, void* d_ws, size_t ws_size,
                              hipStream_t stream) {
    const float* param = (const float*)d_in[0];
    const float* T10   = (const float*)d_in[1];
    const float* cp    = (const float*)d_in[2];
    float*       out   = (float*)d_out;

    const int threads = 256;
    const int blocks  = Bn / R;            // 1024
    etofts_kernel<<<blocks, threads, 0, stream>>>(param, T10, cp, out);
}

// Round 3
// 273.732 us; speedup vs baseline: 1.0983x; 1.0474x over previous
//
#include <hip/hip_runtime.h>

// DCE-MRI eTofts forward model — wave-autonomous pipelined version.
// param: [B,3] f32, T10: [B,1] f32, cp: [B,T] f32  ->  out: [B,T] f32
//
// Block = 128 threads = 2 waves; each wave owns 64 consecutive rows and a
// PRIVATE LDS region (no cross-wave data sharing, barriers only align
// symmetric work). T tiled 4 x 28. Each wave prefetches tile k+1 into
// registers (7 float4/lane, coalesced) while computing tile k from LDS,
// hiding HBM latency inside the wave itself.
// LDS layout transposed: lds[t*65 + row]; compute reads lds[t*65+lane]
// (bank = (t+lane)%32, 2 lanes/bank -> conflict-free per m136).

static constexpr int   Bn    = 262144;
static constexpr int   Tn    = 112;
static constexpr int   TT    = 28;         // timesteps per tile
static constexpr int   NT    = Tn / TT;    // 4 tiles
static constexpr int   LP    = 65;         // LDS stride between t-rows (pad)
static constexpr float TRc   = 0.005f;
static constexpr float DELTT = 0.075f;                 // 4.5/60
static constexpr float R1R   = 4.5f;
static constexpr float SIN_A = 0.25881904510252074f;   // sin(15 deg)
static constexpr float COS_A = 0.9659258262890683f;    // cos(15 deg)

__global__ __launch_bounds__(128) void etofts_kernel(
    const float* __restrict__ param,
    const float* __restrict__ T10,
    const float* __restrict__ cp,
    float* __restrict__ out)
{
    __shared__ float lds[2][TT * LP];      // 2 x 7280 B = 14560 B

    const int tid = threadIdx.x;
    const int w   = tid >> 6;              // wave id within block
    const int l   = tid & 63;              // lane
    float* __restrict__ sl = lds[w];       // wave-private LDS region

    const int b0 = blockIdx.x * 128 + w * 64;  // this wave's first row
    const int b  = b0 + l;                     // this lane's own row

    // Parameter scaling + clamping
    const float ktrans = fminf(fmaxf(param[3 * b + 0] * 0.2f, 1e-5f), 0.2f);
    const float vp     = fminf(fmaxf(param[3 * b + 1] * 0.1f, 0.0005f), 0.1f);
    const float ve     = fminf(fmaxf(param[3 * b + 2] * 0.6f, 0.04f), 0.6f);
    const float decay  = __expf(-(ktrans / ve) * DELTT);
    const float r10    = 1.0f / T10[b];

    // ---- prefetch tile 0 into registers (coalesced float4) ----
    // idx = i*64 + l in [0,448): row = idx/7 in [0,64), c4 = idx%7
    float4 r[7];
    #pragma unroll
    for (int i = 0; i < 7; ++i) {
        const int idx = i * 64 + l;
        const int row = idx / 7;
        const int c4  = idx - row * 7;
        r[i] = *(const float4*)(cp + (size_t)(b0 + row) * Tn + c4 * 4);
    }

    float c = 0.0f;                        // IIR state across tiles

    #pragma unroll
    for (int tile = 0; tile < NT; ++tile) {
        // ---- stage prefetched registers into transposed LDS ----
        #pragma unroll
        for (int i = 0; i < 7; ++i) {
            const int idx = i * 64 + l;
            const int row = idx / 7;
            const int c4  = idx - row * 7;
            const int tb  = c4 * 4;
            sl[(tb + 0) * LP + row] = r[i].x;
            sl[(tb + 1) * LP + row] = r[i].y;
            sl[(tb + 2) * LP + row] = r[i].z;
            sl[(tb + 3) * LP + row] = r[i].w;
        }
        __syncthreads();

        // ---- issue next tile's loads NOW (hide HBM latency behind compute) ----
        if (tile + 1 < NT) {
            #pragma unroll
            for (int i = 0; i < 7; ++i) {
                const int idx = i * 64 + l;
                const int row = idx / 7;
                const int c4  = idx - row * 7;
                r[i] = *(const float4*)(cp + (size_t)(b0 + row) * Tn
                                        + (tile + 1) * TT + c4 * 4);
            }
        }

        // ---- compute in place (own column: no cross-lane race) ----
        #pragma unroll
        for (int t = 0; t < TT; ++t) {
            const float cpt = sl[t * LP + l];
            c = fmaf(c, decay, cpt * DELTT);             // IIR recurrence
            const float ct = fmaf(c, ktrans, vp * cpt);  // vp*cp + ce
            const float E  = __expf(-TRc * fmaf(R1R, ct, r10));
            sl[t * LP + l] = __fdividef((1.0f - E) * (SIN_A * 20.0f),
                                        fmaf(-E, COS_A, 1.0f));
        }
        __syncthreads();

        // ---- coalesced store from transposed LDS ----
        #pragma unroll
        for (int i = 0; i < 7; ++i) {
            const int idx = i * 64 + l;
            const int row = idx / 7;
            const int c4  = idx - row * 7;
            const int tb  = c4 * 4;
            float4 o;
            o.x = sl[(tb + 0) * LP + row];
            o.y = sl[(tb + 1) * LP + row];
            o.z = sl[(tb + 2) * LP + row];
            o.w = sl[(tb + 3) * LP + row];
            *(float4*)(out + (size_t)(b0 + row) * Tn + tile * TT + c4 * 4) = o;
        }
        __syncthreads();   // protect LDS before next tile's staging overwrites
    }
}

extern "C" void kernel_launch(void* const* d_in, const int* in_sizes, int n_in,
                              void* d_out, int out_size, void* d_ws, size_t ws_size,
                              hipStream_t stream) {
    const float* param = (const float*)d_in[0];
    const float* T10   = (const float*)d_in[1];
    const float* cp    = (const float*)d_in[2];
    float*       out   = (float*)d_out;

    const int threads = 128;
    const int blocks  = Bn / 128;          // 2048
    etofts_kernel<<<blocks, threads, 0, stream>>>(param, T10, cp, out);
}